// Round 1
// baseline (39.095 us; speedup 1.0000x reference)
//
#include <hip/hip_runtime.h>

// DGT forward, collapsed: per-sample binary-tree descent on sign(pred_z),
// then out = softmax(W_or[:, leaf]), std = clip(action_stds[:, leaf], -20, 2).
//
// Shapes: x [65536,256] f32, W_pred [1023,256], b_pred [1023],
//         W_or [16,1024], action_stds [16,1024].
// d_out = [out (65536x16) | std (65536x16)] f32.

#define BATCH   65536
#define IN_DIM  256
#define HEIGHT  10
#define LEAF    1024
#define OUT_DIM 16

// 256 threads = 4 waves; each wave handles 4 samples via 16-lane groups.
// 16 samples per block -> 4096 blocks.
__global__ __launch_bounds__(256, 4) void dgt_kernel(
    const float* __restrict__ x,
    const float* __restrict__ W_pred,
    const float* __restrict__ b_pred,
    const float* __restrict__ W_or,
    const float* __restrict__ a_std,
    float* __restrict__ out)
{
    const int lane = threadIdx.x & 63;
    const int wid  = threadIdx.x >> 6;   // wave in block (0..3)
    const int g    = lane >> 4;          // sample group within wave (0..3)
    const int l    = lane & 15;          // lane within group (0..15)
    const int sample = (blockIdx.x * 4 + wid) * 4 + g;

    // Load this sample's x row into registers as f64.
    // Element e = k*64 + l*4 + c  ->  xr[k*4+c]; each k is a coalesced
    // 256B segment per 16-lane group (float4 per lane).
    double xr[16];
    const float* xrow = x + (size_t)sample * IN_DIM;
    #pragma unroll
    for (int k = 0; k < 4; ++k) {
        float4 v = *reinterpret_cast<const float4*>(xrow + k * 64 + l * 4);
        xr[k*4+0] = (double)v.x; xr[k*4+1] = (double)v.y;
        xr[k*4+2] = (double)v.z; xr[k*4+3] = (double)v.w;
    }

    // Tree descent: node j at level i; pred_z[j] >= 0 -> left child.
    int pos  = 0;   // position within current level
    int node = 0;   // heap index of current node
    #pragma unroll
    for (int lvl = 0; lvl < HEIGHT; ++lvl) {
        const float* wrow = W_pred + (size_t)node * IN_DIM;
        double acc = 0.0;
        #pragma unroll
        for (int k = 0; k < 4; ++k) {
            float4 w = *reinterpret_cast<const float4*>(wrow + k * 64 + l * 4);
            acc += xr[k*4+0] * (double)w.x;
            acc += xr[k*4+1] * (double)w.y;
            acc += xr[k*4+2] * (double)w.z;
            acc += xr[k*4+3] * (double)w.w;
        }
        // Butterfly reduce across the 16-lane group (bitwise-uniform result:
        // each step both partners compute the same commutative add).
        #pragma unroll
        for (int off = 8; off > 0; off >>= 1)
            acc += __shfl_xor(acc, off, 64);
        acc += (double)b_pred[node];
        pos  = 2 * pos + (acc < 0.0 ? 1 : 0);
        node = (2 << lvl) - 1 + pos;   // first node of next level + pos
    }
    const int leaf = pos;  // in [0, 1024)

    // out = softmax over 16 classes of W_or[:, leaf]; one class per lane.
    float z = W_or[l * LEAF + leaf];
    float m = z;
    #pragma unroll
    for (int off = 8; off > 0; off >>= 1)
        m = fmaxf(m, __shfl_xor(m, off, 64));
    float e = __expf(z - m);
    float s = e;
    #pragma unroll
    for (int off = 8; off > 0; off >>= 1)
        s += __shfl_xor(s, off, 64);
    // Stores: sample = base + g, so wave-wide address = base*16 + lane
    // -> fully contiguous 256B per wave.
    out[(size_t)sample * OUT_DIM + l] = e / s;

    float sd = a_std[l * LEAF + leaf];
    sd = fminf(fmaxf(sd, -20.0f), 2.0f);
    out[(size_t)BATCH * OUT_DIM + (size_t)sample * OUT_DIM + l] = sd;
}

extern "C" void kernel_launch(void* const* d_in, const int* in_sizes, int n_in,
                              void* d_out, int out_size, void* d_ws, size_t ws_size,
                              hipStream_t stream) {
    const float* x      = (const float*)d_in[0];
    const float* W_pred = (const float*)d_in[1];
    const float* b_pred = (const float*)d_in[2];
    const float* W_or   = (const float*)d_in[3];
    const float* a_std  = (const float*)d_in[4];
    float* out = (float*)d_out;

    dim3 grid(BATCH / 16);   // 4096 blocks, 16 samples each
    dim3 block(256);
    hipLaunchKernelGGL(dgt_kernel, grid, block, 0, stream,
                       x, W_pred, b_pred, W_or, a_std, out);
}